// Round 5
// baseline (167.771 us; speedup 1.0000x reference)
//
#include <hip/hip_runtime.h>

// NeuSSampler PDF importance resampling — v5: PERSISTENT waves + software
// prefetch, SoA LDS payloads (conflict-free), v4 scatter-max inversion math.
//
// v2/v3/v4 post-mortem: three radically different instruction mixes all land
// at 50-55us with SIMD issue <45% busy => NOT issue-bound. Wave lifetime
// (~5200 cyc) >> critical path (~1300 cyc): the shared cost is per-wave cold
// start (one full memory latency + serial scan->shfl->LDS chain) paid once
// per ray, 131072 times, with no pipelining. v5:
//   - 2048 blocks (8/CU, fills 32 waves/CU), each wave grid-strides 16 rays
//   - next ray's global loads issued BEFORE current ray's compute: load
//     latency hides under compute, cold start amortized 16x
//   - payload store switched AoS->SoA: ds_write_b64 at 8B stride = 2
//     lanes/bank = conflict-free (v4's float4 AoS writes were 16-way,
//     3.5M conflict cycles)
//   - inversion math identical to v4 (validated): owner(j) = largest k with
//     jf(cdf[k]) <= j via one ds_max_u32 per segment + 6-step DPP prefix-max
//
// All LDS wave-private; same-wave DS ops execute in order => no barriers,
// one lgkmcnt(0) drain per iteration between scatter and read-back.
// Degenerate segments: d<=0 -> rcp -> inf/NaN -> fmaxf(NaN,0)=0 /
// fminf(inf,1)=1 reproduces reference nan_to_num + clip gather semantics.

#define DPP_FADD(x, ctrl, rmask)                                             \
    ((x) + __int_as_float(__builtin_amdgcn_update_dpp(                       \
               0, __float_as_int(x), (ctrl), (rmask), 0xf, true)))

__device__ __forceinline__ unsigned umax_(unsigned a, unsigned b) {
    return a > b ? a : b;
}

#define DPP_UMAX(x, ctrl, rmask)                                             \
    (umax_((x), (unsigned)__builtin_amdgcn_update_dpp(                       \
               0, (int)(x), (ctrl), (rmask), 0xf, true)))

struct RayIn {
    float2 wpair;   // weights[2l], weights[2l+1]
    float2 bpair;   // bins[2l], bins[2l+1]
    float  bl;      // bins[128] (lane 63 only; others 0)
    float  nearv;
    float  farv;
};

__device__ __forceinline__ RayIn load_ray(const float* __restrict__ weights,
                                          const float* __restrict__ bins_g,
                                          const float* __restrict__ nears,
                                          const float* __restrict__ fars,
                                          int uray, int lane)
{
    RayIn r;
    r.wpair = reinterpret_cast<const float2*>(weights + (size_t)uray * 128)[lane];
    const float* brow = bins_g + (size_t)uray * 129;
    r.bpair = reinterpret_cast<const float2*>(brow)[lane];
    r.bl    = (lane == 63) ? brow[128] : 0.0f;   // 1-lane vector load (vmcnt)
    r.nearv = nears[uray];                       // uniform -> s_load
    r.farv  = fars[uray];
    return r;
}

__global__ __launch_bounds__(256) void neus_sampler_kernel(
    const float* __restrict__ weights,
    const float* __restrict__ bins_g,
    const float* __restrict__ nears,
    const float* __restrict__ fars,
    float* __restrict__ out,
    int R)
{
    constexpr int NB = 65;    // output samples per ray
    constexpr float HPAD = 1e-5f;

    // SoA payloads: ds_write_b64 per array (8B stride across lanes -> 2
    // lanes/bank -> conflict-free). All wave-private.
    __shared__ float    payc[4][128];   // c_start
    __shared__ float    payd[4][128];   // c_end - c_start
    __shared__ float    payb[4][128];   // fmaf(b_start, fmn, near)
    __shared__ float    pays[4][128];   // (b_end - b_start) * fmn
    __shared__ unsigned best[4][66];    // scatter-max target; [65]=dump slot

    const int lane = threadIdx.x & 63;
    const int wv   = threadIdx.x >> 6;
    const int gw   = blockIdx.x * 4 + wv;       // global wave id
    const int stride = gridDim.x * 4;
    if (gw >= R) return;                        // wave-uniform

    // first query index j with u_j >= c  (u_j = (2j+1)/130)
    auto jf = [](float c) -> int {
        int j = (int)ceilf(fmaf(65.0f, c, -0.5f));
        return j < 0 ? 0 : (j > NB ? NB : j);
    };

    int ray = gw;
    RayIn cur = load_ray(weights, bins_g, nears, fars,
                         __builtin_amdgcn_readfirstlane(ray), lane);

    while (true) {
        const int nray = ray + stride;
        const bool have = (nray < R);           // wave-uniform
        RayIn nxt;
        if (have)                               // prefetch: issue loads now,
            nxt = load_ray(weights, bins_g, nears, fars,   // consume next iter
                           __builtin_amdgcn_readfirstlane(nray), lane);

        // ---------------- process current ray ----------------
        const int uray = __builtin_amdgcn_readfirstlane(ray);

        // init best[0..65] = 0 (segment 0 is a valid default: j_start(0)=0)
        if (lane < 33)
            *reinterpret_cast<unsigned long long*>(&best[wv][2 * lane]) = 0ull;

        const float w1 = cur.wpair.y + HPAD;
        float ps = (cur.wpair.x + HPAD) + w1;   // pair sum

        // wave64 inclusive scan (DPP): ps = cumsum(w)[2l+1]
        ps = DPP_FADD(ps, 0x111, 0xf);  // row_shr:1
        ps = DPP_FADD(ps, 0x112, 0xf);  // row_shr:2
        ps = DPP_FADD(ps, 0x114, 0xf);  // row_shr:4
        ps = DPP_FADD(ps, 0x118, 0xf);  // row_shr:8
        ps = DPP_FADD(ps, 0x142, 0xa);  // row_bcast:15 -> rows 1,3
        ps = DPP_FADD(ps, 0x143, 0xc);  // row_bcast:31 -> rows 2,3

        const float total =
            __int_as_float(__builtin_amdgcn_readlane(__float_as_int(ps), 63));
        const float padding = fmaxf(1e-5f - total, 0.0f);
        const float padc    = padding * (1.0f / 128.0f);
        const float inv     = __builtin_amdgcn_rcpf(total + padding);

        // per-lane cdf edges (registers only)
        const float c_hi  = fminf(1.0f, fmaf((float)(2 * lane + 2), padc, ps) * inv);
        const float c_mid = fminf(1.0f, fmaf((float)(2 * lane + 1), padc, ps - w1) * inv);
        float c_lo = __shfl_up(c_hi, 1, 64);
        if (lane == 0) c_lo = 0.0f;             // cdf[0]
        float b2 = __shfl_down(cur.bpair.x, 1, 64);   // bins[2l+2]
        if (lane == 63) b2 = cur.bl;            // bins[128]

        const float nearv = cur.nearv;
        const float fmn   = cur.farv - nearv;

        // payloads at static addresses, SoA (each pair -> one ds_write_b64)
        payc[wv][2 * lane]     = c_lo;
        payc[wv][2 * lane + 1] = c_mid;
        payd[wv][2 * lane]     = c_mid - c_lo;
        payd[wv][2 * lane + 1] = c_hi - c_mid;
        payb[wv][2 * lane]     = fmaf(cur.bpair.x, fmn, nearv);
        payb[wv][2 * lane + 1] = fmaf(cur.bpair.y, fmn, nearv);
        pays[wv][2 * lane]     = (cur.bpair.y - cur.bpair.x) * fmn;
        pays[wv][2 * lane + 1] = (b2 - cur.bpair.y) * fmn;

        // scatter-max: one ds_max_u32 per segment, no loops
        atomicMax(&best[wv][jf(c_lo)],  (unsigned)(2 * lane));
        atomicMax(&best[wv][jf(c_mid)], (unsigned)(2 * lane + 1));

        // drain DS (wave-private; same-wave DS ops are in-order)
        asm volatile("s_waitcnt lgkmcnt(0)" ::: "memory");

        // prefix-max scan: M_j = max(best[0..j]) = owner segment of slot j
        unsigned m = best[wv][lane];
        m = DPP_UMAX(m, 0x111, 0xf);
        m = DPP_UMAX(m, 0x112, 0xf);
        m = DPP_UMAX(m, 0x114, 0xf);
        m = DPP_UMAX(m, 0x118, 0xf);
        m = DPP_UMAX(m, 0x142, 0xa);
        m = DPP_UMAX(m, 0x143, 0xc);

        // uniform epilogue: lane j computes output j, coalesced 256B store
        float* const orow = out + (size_t)uray * NB;
        {
            const float px = payc[wv][m], py = payd[wv][m];
            const float pz = payb[wv][m], pw = pays[wv][m];
            const float u  = (float)(2 * lane + 1) * (1.0f / 130.0f);
            const float t  = (u - px) * __builtin_amdgcn_rcpf(py);
            const float tc = fminf(fmaxf(t, 0.0f), 1.0f);   // NaN-safe: ->0
            orow[lane] = fmaf(tc, pw, pz);
        }
        if (lane == 63) {                                   // output 64
            const unsigned m64 = umax_(m, best[wv][64]);
            const float px = payc[wv][m64], py = payd[wv][m64];
            const float pz = payb[wv][m64], pw = pays[wv][m64];
            const float t  = (129.0f / 130.0f - px) * __builtin_amdgcn_rcpf(py);
            const float tc = fminf(fmaxf(t, 0.0f), 1.0f);
            orow[64] = fmaf(tc, pw, pz);
        }
        // -----------------------------------------------------

        if (!have) break;
        cur = nxt;
        ray = nray;
    }
}

extern "C" void kernel_launch(void* const* d_in, const int* in_sizes, int n_in,
                              void* d_out, int out_size, void* d_ws, size_t ws_size,
                              hipStream_t stream) {
    const float* weights = (const float*)d_in[0];   // [R,128,1]
    const float* ebins   = (const float*)d_in[1];   // [R,129]
    const float* nears   = (const float*)d_in[2];   // [R,1]
    const float* fars    = (const float*)d_in[3];   // [R,1]
    float* out = (float*)d_out;                     // [R,65]
    const int R = in_sizes[0] / 128;
    int blocks = (R + 3) / 4;                       // 4 rays (waves) per block
    if (blocks > 2048) blocks = 2048;               // persistent: 8 blocks/CU
    hipLaunchKernelGGL(neus_sampler_kernel, dim3(blocks), dim3(256), 0, stream,
                       weights, ebins, nears, fars, out, R);
}